// Round 7
// baseline (308.819 us; speedup 1.0000x reference)
//
#include <hip/hip_runtime.h>
#include <hip/hip_bf16.h>

#define N_NODES 100000
#define N_EDGES 640000
#define DIM 128
#define N_LAYERS 3
#define N_GRAPHS 128
#define N_OUT 10
#define SCAN_BLK 1024  // elements per scan block (256 thr x 4)
#define N_SCAN_BLKS ((N_NODES + SCAN_BLK - 1) / SCAN_BLK)  // 98
#define PCHUNK 128     // rows per pool block

typedef _Float16 h4 __attribute__((ext_vector_type(4)));
typedef _Float16 h2 __attribute__((ext_vector_type(2)));
typedef _Float16 h8 __attribute__((ext_vector_type(8)));
typedef float f32x4 __attribute__((ext_vector_type(4)));

struct EdgeRec { int s; unsigned int w2; };  // w2 = packed half2(w, w)

// ---------------- degree / norm ----------------

__global__ void hist_dst(const int* __restrict__ ei, int* __restrict__ cnt) {
    int e = blockIdx.x * blockDim.x + threadIdx.x;
    if (e < N_EDGES) atomicAdd(&cnt[ei[N_EDGES + e]], 1);
}

__global__ void make_dinv(const int* __restrict__ cnt, float* __restrict__ dinv) {
    int i = blockIdx.x * blockDim.x + threadIdx.x;
    if (i < N_NODES) dinv[i] = rsqrtf((float)(cnt[i] + 1));  // +1 self-loop
}

// ---------------- exclusive scan (3 kernels) ----------------

__global__ void scan1(const int* __restrict__ cnt, int* __restrict__ off, int* __restrict__ bsum) {
    __shared__ int tmp[256];
    int base = blockIdx.x * SCAN_BLK + threadIdx.x * 4;
    int c[4];
    #pragma unroll
    for (int k = 0; k < 4; ++k) c[k] = (base + k < N_NODES) ? cnt[base + k] : 0;
    int tot = c[0] + c[1] + c[2] + c[3];
    tmp[threadIdx.x] = tot;
    __syncthreads();
    int val = tot;
    for (int d = 1; d < 256; d <<= 1) {
        int add = (threadIdx.x >= d) ? tmp[threadIdx.x - d] : 0;
        __syncthreads();
        val += add;
        tmp[threadIdx.x] = val;
        __syncthreads();
    }
    int ex = val - tot;
    int e1 = ex + c[0], e2 = e1 + c[1], e3 = e2 + c[2];
    if (base + 0 < N_NODES) off[base + 0] = ex;
    if (base + 1 < N_NODES) off[base + 1] = e1;
    if (base + 2 < N_NODES) off[base + 2] = e2;
    if (base + 3 < N_NODES) off[base + 3] = e3;
    if (threadIdx.x == 255) bsum[blockIdx.x] = val;
}

__global__ void scan2(int* __restrict__ bsum) {
    if (threadIdx.x == 0 && blockIdx.x == 0) {
        int acc = 0;
        for (int i = 0; i < N_SCAN_BLKS; ++i) { int v = bsum[i]; bsum[i] = acc; acc += v; }
    }
}

__global__ void scan3(int* __restrict__ off, const int* __restrict__ bsum) {
    int i = blockIdx.x * blockDim.x + threadIdx.x;
    if (i < N_NODES) off[i] += bsum[i / SCAN_BLK];
    if (i == 0) off[N_NODES] = N_EDGES;
}

// ---------------- CSR fill ----------------

__global__ void fill_csr(const int* __restrict__ ei, const float* __restrict__ dinv,
                         const int* __restrict__ off, int* __restrict__ cursor,
                         EdgeRec* __restrict__ csr) {
    int e = blockIdx.x * blockDim.x + threadIdx.x;
    if (e >= N_EDGES) return;
    int s = ei[e], d = ei[N_EDGES + e];
    int pos = off[d] + atomicAdd(&cursor[d], 1);
    float w = dinv[s] * dinv[d];
    h2 w2; w2.x = (_Float16)w; w2.y = (_Float16)w;
    EdgeRec r; r.s = s; r.w2 = *(unsigned int*)&w2;
    csr[pos] = r;
}

// ---------------- W prep: transpose + fp16 + XOR-swizzle ----------------
// Wt_swz[l][n][u'] (u' = 8B unit) where u' = u ^ (n&31), unit u holds W[u*4..u*4+3][n].

__global__ void wt_prep(const float* __restrict__ Ws, _Float16* __restrict__ wt) {
    int t = blockIdx.x * blockDim.x + threadIdx.x;  // (l, n, u): 3*128*32
    if (t >= N_LAYERS * DIM * 32) return;
    int u = t & 31;
    int n = (t >> 5) & 127;
    int l = t >> 12;
    const float* W = Ws + (size_t)l * DIM * DIM;
    int k0 = u * 4;
    h4 v;
    v.x = (_Float16)W[(k0 + 0) * DIM + n];
    v.y = (_Float16)W[(k0 + 1) * DIM + n];
    v.z = (_Float16)W[(k0 + 2) * DIM + n];
    v.w = (_Float16)W[(k0 + 3) * DIM + n];
    int du = u ^ (n & 31);
    ((h4*)wt)[(size_t)l * 4096 + n * 32 + du] = v;
}

// ---------------- MFMA dense transform: out = in @ W  (fp16 out, f32 acc) ----------------
// 32 rows per wave: each A-fragment ds_read feeds two MFMAs.

__device__ __forceinline__ h4 loadfrag(const _Float16* p) { return *(const h4*)p; }
__device__ __forceinline__ h4 loadfrag(const float* p) {
    float4 f = *(const float4*)p;
    h4 v; v.x = (_Float16)f.x; v.y = (_Float16)f.y; v.z = (_Float16)f.z; v.w = (_Float16)f.w;
    return v;
}

template<typename TIN>
__global__ __launch_bounds__(256) void gemm_mfma(const TIN* __restrict__ in,
                                                 const _Float16* __restrict__ wt,
                                                 _Float16* __restrict__ out) {
    __shared__ h4 Wl[4096];  // 32 KB swizzled W^T
    {
        const float4* src = (const float4*)wt;
        float4* dst = (float4*)Wl;
        #pragma unroll
        for (int i = 0; i < 8; ++i) dst[threadIdx.x + i * 256] = src[threadIdx.x + i * 256];
    }
    __syncthreads();

    const int wave = threadIdx.x >> 6;
    const int lane = threadIdx.x & 63;
    const int m0 = blockIdx.x * 128 + wave * 32;
    if (m0 >= N_NODES) return;   // N_NODES % 32 == 0: waves all-valid or all-OOB

    const int row = lane & 15;   // m-offset (B col) / n-offset (A row)
    const int g   = lane >> 4;   // k-group
    const TIN* arow0 = in + (size_t)(m0 + row) * DIM;
    const TIN* arow1 = arow0 + (size_t)16 * DIM;

    f32x4 acc0[8] = {};  // rows m0..m0+15
    f32x4 acc1[8] = {};  // rows m0+16..m0+31

    #pragma unroll
    for (int kc = 0; kc < 8; ++kc) {
        const int k = kc * 16 + g * 4;
        const h4 b0 = loadfrag(arow0 + k);
        const h4 b1 = loadfrag(arow1 + k);
        const int u = kc * 4 + g;
        #pragma unroll
        for (int nb = 0; nb < 8; ++nb) {
            const int n = nb * 16 + row;
            const h4 afrag = Wl[n * 32 + (u ^ (n & 31))];  // A[n][k..k+3]
            acc0[nb] = __builtin_amdgcn_mfma_f32_16x16x16f16(afrag, b0, acc0[nb], 0, 0, 0);
            acc1[nb] = __builtin_amdgcn_mfma_f32_16x16x16f16(afrag, b1, acc1[nb], 0, 0, 0);
        }
    }

    _Float16* orow0 = out + (size_t)(m0 + row) * DIM;
    _Float16* orow1 = orow0 + (size_t)16 * DIM;
    #pragma unroll
    for (int nb = 0; nb < 8; ++nb) {
        h4 v0, v1;
        v0.x = (_Float16)acc0[nb].x; v0.y = (_Float16)acc0[nb].y;
        v0.z = (_Float16)acc0[nb].z; v0.w = (_Float16)acc0[nb].w;
        v1.x = (_Float16)acc1[nb].x; v1.y = (_Float16)acc1[nb].y;
        v1.z = (_Float16)acc1[nb].z; v1.w = (_Float16)acc1[nb].w;
        ((h4*)orow0)[nb * 4 + g] = v0;
        ((h4*)orow1)[nb * 4 + g] = v1;
    }
}

// ---------------- fused aggregate + bias + relu ----------------
// one wave64 per node; 8 groups of 8 lanes: stream = grp&3, half = grp>>2.
// Each group reads a 128B half-row per edge; 4 streams x 2 halves x 2-unroll
// = 16 gathers in flight. fp16 packed accumulation (v_pk_fma_f16).

__device__ __forceinline__ h8 fma_pairs(h8 v, unsigned int w2bits, h8 a) {
    h2 w2 = *(h2*)&w2bits;
    h2* vp = (h2*)&v;
    h2* ap = (h2*)&a;
    #pragma unroll
    for (int p = 0; p < 4; ++p) ap[p] += vp[p] * w2;  // v_pk_fma_f16
    return a;
}

__global__ __launch_bounds__(256) void gather_agg(const _Float16* __restrict__ hw,
                                                  const float* __restrict__ dinv,
                                                  const int* __restrict__ off,
                                                  const EdgeRec* __restrict__ csr,
                                                  const float* __restrict__ bias,
                                                  _Float16* __restrict__ hout) {
    const int i = (blockIdx.x * blockDim.x + threadIdx.x) >> 6;  // node = wave id
    if (i >= N_NODES) return;
    const int lane = threadIdx.x & 63;
    const int grp    = lane >> 3;   // 0..7
    const int stream = grp & 3;     // edge stream
    const int half   = grp >> 2;    // row half (dims half*64 ..)
    const int sub    = lane & 7;    // h8 unit within half
    const int idx8   = half * 8 + sub;   // h8 index in row (16 per row)
    const h8* hw8 = (const h8*)hw;

    const int beg = off[i], end = off[i + 1];
    h8 acc = {};

    if (stream == 3) {  // self-loop message
        float di = dinv[i];
        float w = di * di;
        h2 w2; w2.x = (_Float16)w; w2.y = (_Float16)w;
        acc = fma_pairs(hw8[(size_t)i * 16 + idx8], *(unsigned int*)&w2, acc);
    }

    int j = beg + stream;
    for (; j + 4 < end; j += 8) {
        EdgeRec e0 = csr[j];
        EdgeRec e1 = csr[j + 4];
        h8 v0 = hw8[(size_t)e0.s * 16 + idx8];
        h8 v1 = hw8[(size_t)e1.s * 16 + idx8];
        acc = fma_pairs(v0, e0.w2, acc);
        acc = fma_pairs(v1, e1.w2, acc);
    }
    for (; j < end; j += 4) {
        EdgeRec e0 = csr[j];
        acc = fma_pairs(hw8[(size_t)e0.s * 16 + idx8], e0.w2, acc);
    }

    // f32 reduce across the 4 streams (lane bits 3,4)
    float a[8];
    #pragma unroll
    for (int d = 0; d < 8; ++d) {
        float v = (float)acc[d];
        v += __shfl_xor(v, 8);
        v += __shfl_xor(v, 16);
        a[d] = v;
    }

    if (stream == 0) {  // grp 0 (half 0) and grp 4 (half 1) write their half
        const float4 b0 = *(const float4*)&bias[half * 64 + sub * 8];
        const float4 b1 = *(const float4*)&bias[half * 64 + sub * 8 + 4];
        h8 v;
        v[0] = (_Float16)fmaxf(a[0] + b0.x, 0.0f);
        v[1] = (_Float16)fmaxf(a[1] + b0.y, 0.0f);
        v[2] = (_Float16)fmaxf(a[2] + b0.z, 0.0f);
        v[3] = (_Float16)fmaxf(a[3] + b0.w, 0.0f);
        v[4] = (_Float16)fmaxf(a[4] + b1.x, 0.0f);
        v[5] = (_Float16)fmaxf(a[5] + b1.y, 0.0f);
        v[6] = (_Float16)fmaxf(a[6] + b1.z, 0.0f);
        v[7] = (_Float16)fmaxf(a[7] + b1.w, 0.0f);
        ((h8*)hout)[(size_t)i * 16 + idx8] = v;
    }
}

// ---------------- chunked segmented pool (batch sorted) ----------------

__global__ __launch_bounds__(256) void pool_chunk(const _Float16* __restrict__ h,
                                                  const int* __restrict__ batch,
                                                  float* __restrict__ pooled) {
    const int base = blockIdx.x * PCHUNK;
    const int t = threadIdx.x;
    const int lane4 = t & 31;    // dims lane4*4 .. +3
    const int rgrp = t >> 5;     // 0..7
    const h4* hp = (const h4*)h; // row stride 32

    float a0 = 0.f, a1 = 0.f, a2 = 0.f, a3 = 0.f;
    int cur = -1;
    const int rend = (base + PCHUNK < N_NODES) ? base + PCHUNK : N_NODES;
    for (int r = base + rgrp; r < rend; r += 8) {
        int b = batch[r];
        if (b != cur) {
            if (cur >= 0) {
                float* pp = &pooled[cur * DIM + lane4 * 4];
                atomicAdd(pp + 0, a0); atomicAdd(pp + 1, a1);
                atomicAdd(pp + 2, a2); atomicAdd(pp + 3, a3);
            }
            cur = b; a0 = a1 = a2 = a3 = 0.f;
        }
        h4 v = hp[(size_t)r * 32 + lane4];
        a0 += (float)v.x; a1 += (float)v.y; a2 += (float)v.z; a3 += (float)v.w;
    }
    if (cur >= 0) {
        float* pp = &pooled[cur * DIM + lane4 * 4];
        atomicAdd(pp + 0, a0); atomicAdd(pp + 1, a1);
        atomicAdd(pp + 2, a2); atomicAdd(pp + 3, a3);
    }
}

// ---------------- head ----------------

__global__ void mlp_head(const float* __restrict__ pooled, const float* __restrict__ Wm,
                         const float* __restrict__ bm, float* __restrict__ out) {
    int t = blockIdx.x * blockDim.x + threadIdx.x;
    if (t >= N_GRAPHS * N_OUT) return;
    int b = t / N_OUT;
    int o = t % N_OUT;
    float acc = bm[o];
    #pragma unroll 8
    for (int k = 0; k < DIM; ++k) acc += pooled[b * DIM + k] * Wm[k * N_OUT + o];
    out[t] = acc;
}

// ---------------- launch ----------------

extern "C" void kernel_launch(void* const* d_in, const int* in_sizes, int n_in,
                              void* d_out, int out_size, void* d_ws, size_t ws_size,
                              hipStream_t stream) {
    const float* x     = (const float*)d_in[0];
    const int*   ei    = (const int*)d_in[1];
    const int*   batch = (const int*)d_in[2];
    const float* Ws    = (const float*)d_in[3];
    const float* bs    = (const float*)d_in[4];
    const float* Wm    = (const float*)d_in[5];
    const float* bm    = (const float*)d_in[6];
    float* out = (float*)d_out;

    // workspace carve-up (16B aligned regions; cnt+cursor adjacent for one memset)
    char* p = (char*)d_ws;
    int*      cnt     = (int*)p;        p += N_NODES * 4;
    int*      cursor  = (int*)p;        p += N_NODES * 4;
    float*    dinv    = (float*)p;      p += N_NODES * 4;
    int*      csr_off = (int*)p;        p += (N_NODES + 16) * 4;
    int*      bsum    = (int*)p;        p += 128 * 4;
    _Float16* wt      = (_Float16*)p;   p += (size_t)N_LAYERS * DIM * DIM * 2;  // swizzled W^T fp16
    EdgeRec*  csr     = (EdgeRec*)p;    p += (size_t)N_EDGES * 8;
    _Float16* bufA    = (_Float16*)p;   p += (size_t)N_NODES * DIM * 2;  // hw
    _Float16* bufB    = (_Float16*)p;   p += (size_t)N_NODES * DIM * 2;  // h
    float*    pooled  = (float*)p;      p += N_GRAPHS * DIM * 4;

    const int nnode_blk = (N_NODES + 255) / 256;
    const int nedge_blk = (N_EDGES + 255) / 256;

    hipMemsetAsync(cnt, 0, N_NODES * 8, stream);  // cnt + cursor
    hipMemsetAsync(pooled, 0, N_GRAPHS * DIM * 4, stream);

    hist_dst<<<nedge_blk, 256, 0, stream>>>(ei, cnt);
    make_dinv<<<nnode_blk, 256, 0, stream>>>(cnt, dinv);
    wt_prep<<<(N_LAYERS * DIM * 32 + 255) / 256, 256, 0, stream>>>(Ws, wt);

    scan1<<<N_SCAN_BLKS, 256, 0, stream>>>(cnt, csr_off, bsum);
    scan2<<<1, 64, 0, stream>>>(bsum);
    scan3<<<nnode_blk, 256, 0, stream>>>(csr_off, bsum);

    fill_csr<<<nedge_blk, 256, 0, stream>>>(ei, dinv, csr_off, cursor, csr);

    const int gemm_grid = (N_NODES + 127) / 128;         // 782 (last block wave-guarded)
    const int gather_grid = (N_NODES * 64 + 255) / 256;  // one wave per node
    for (int l = 0; l < N_LAYERS; ++l) {
        if (l == 0) gemm_mfma<float><<<gemm_grid, 256, 0, stream>>>(x, wt, bufA);
        else        gemm_mfma<_Float16><<<gemm_grid, 256, 0, stream>>>(bufB, wt + (size_t)l * DIM * DIM, bufA);
        gather_agg<<<gather_grid, 256, 0, stream>>>(bufA, dinv, csr_off, csr, bs + l * DIM, bufB);
    }

    pool_chunk<<<(N_NODES + PCHUNK - 1) / PCHUNK, 256, 0, stream>>>(bufB, batch, pooled);
    mlp_head<<<(N_GRAPHS * N_OUT + 255) / 256, 256, 0, stream>>>(pooled, Wm, bm, out);
}

// Round 8
// 301.435 us; speedup vs baseline: 1.0245x; 1.0245x over previous
//
#include <hip/hip_runtime.h>
#include <hip/hip_bf16.h>

#define N_NODES 100000
#define N_EDGES 640000
#define DIM 128
#define N_LAYERS 3
#define N_GRAPHS 128
#define N_OUT 10
#define SCAN_BLK 1024  // elements per scan block (256 thr x 4)
#define N_SCAN_BLKS ((N_NODES + SCAN_BLK - 1) / SCAN_BLK)  // 98
#define PCHUNK 128     // rows per pool block

typedef _Float16 h4 __attribute__((ext_vector_type(4)));
typedef _Float16 h2 __attribute__((ext_vector_type(2)));
typedef _Float16 h8 __attribute__((ext_vector_type(8)));
typedef float f32x4 __attribute__((ext_vector_type(4)));

// ---------------- degree histogram ----------------

__global__ void hist_dst(const int* __restrict__ ei, int* __restrict__ cnt) {
    int e = blockIdx.x * blockDim.x + threadIdx.x;
    if (e < N_EDGES) atomicAdd(&cnt[ei[N_EDGES + e]], 1);
}

// ---------------- exclusive scan (3 kernels) + fused dinv ----------------

__global__ void scan1(const int* __restrict__ cnt, int* __restrict__ off, int* __restrict__ bsum,
                      float* __restrict__ dinv) {
    __shared__ int tmp[256];
    int base = blockIdx.x * SCAN_BLK + threadIdx.x * 4;
    int c[4];
    #pragma unroll
    for (int k = 0; k < 4; ++k) c[k] = (base + k < N_NODES) ? cnt[base + k] : 0;
    // fused: dinv = rsqrt(deg+1)  (self-loop makes deg >= 1)
    #pragma unroll
    for (int k = 0; k < 4; ++k)
        if (base + k < N_NODES) dinv[base + k] = rsqrtf((float)(c[k] + 1));
    int tot = c[0] + c[1] + c[2] + c[3];
    tmp[threadIdx.x] = tot;
    __syncthreads();
    int val = tot;
    for (int d = 1; d < 256; d <<= 1) {
        int add = (threadIdx.x >= d) ? tmp[threadIdx.x - d] : 0;
        __syncthreads();
        val += add;
        tmp[threadIdx.x] = val;
        __syncthreads();
    }
    int ex = val - tot;
    int e1 = ex + c[0], e2 = e1 + c[1], e3 = e2 + c[2];
    if (base + 0 < N_NODES) off[base + 0] = ex;
    if (base + 1 < N_NODES) off[base + 1] = e1;
    if (base + 2 < N_NODES) off[base + 2] = e2;
    if (base + 3 < N_NODES) off[base + 3] = e3;
    if (threadIdx.x == 255) bsum[blockIdx.x] = val;
}

// wave-parallel scan of the 98 block sums (one block, 128 threads)
__global__ void scan2(int* __restrict__ bsum) {
    __shared__ int tmp[128];
    int t = threadIdx.x;
    int v = (t < N_SCAN_BLKS) ? bsum[t] : 0;
    int own = v;
    tmp[t] = v;
    __syncthreads();
    for (int d = 1; d < 128; d <<= 1) {
        int add = (t >= d) ? tmp[t - d] : 0;
        __syncthreads();
        v += add;
        tmp[t] = v;
        __syncthreads();
    }
    if (t < N_SCAN_BLKS) bsum[t] = v - own;  // exclusive
}

__global__ void scan3(int* __restrict__ off, const int* __restrict__ bsum) {
    int i = blockIdx.x * blockDim.x + threadIdx.x;
    if (i < N_NODES) off[i] += bsum[i / SCAN_BLK];
    if (i == 0) off[N_NODES] = N_EDGES;
}

// ---------------- CSR fill (src only; weights factorized away) ----------------

__global__ void fill_csr(const int* __restrict__ ei, const int* __restrict__ off,
                         int* __restrict__ cursor, int* __restrict__ csr_src) {
    int e = blockIdx.x * blockDim.x + threadIdx.x;
    if (e >= N_EDGES) return;
    int s = ei[e], d = ei[N_EDGES + e];
    int pos = off[d] + atomicAdd(&cursor[d], 1);
    csr_src[pos] = s;
}

// ---------------- W prep: transpose + fp16 + XOR-swizzle ----------------
// Wt_swz[l][n][u'] (u' = 8B unit) where u' = u ^ (n&31), unit u holds W[u*4..u*4+3][n].

__global__ void wt_prep(const float* __restrict__ Ws, _Float16* __restrict__ wt) {
    int t = blockIdx.x * blockDim.x + threadIdx.x;  // (l, n, u): 3*128*32
    if (t >= N_LAYERS * DIM * 32) return;
    int u = t & 31;
    int n = (t >> 5) & 127;
    int l = t >> 12;
    const float* W = Ws + (size_t)l * DIM * DIM;
    int k0 = u * 4;
    h4 v;
    v.x = (_Float16)W[(k0 + 0) * DIM + n];
    v.y = (_Float16)W[(k0 + 1) * DIM + n];
    v.z = (_Float16)W[(k0 + 2) * DIM + n];
    v.w = (_Float16)W[(k0 + 3) * DIM + n];
    int du = u ^ (n & 31);
    ((h4*)wt)[(size_t)l * 4096 + n * 32 + du] = v;
}

// ---------------- MFMA dense transform: out = dinv * (in @ W)  (fp16 out, f32 acc) ----------------
// R4 structure: 16 rows per wave, 64 rows per block.

__device__ __forceinline__ h4 loadfrag(const _Float16* p) { return *(const h4*)p; }
__device__ __forceinline__ h4 loadfrag(const float* p) {
    float4 f = *(const float4*)p;
    h4 v; v.x = (_Float16)f.x; v.y = (_Float16)f.y; v.z = (_Float16)f.z; v.w = (_Float16)f.w;
    return v;
}

template<typename TIN>
__global__ __launch_bounds__(256) void gemm_mfma(const TIN* __restrict__ in,
                                                 const _Float16* __restrict__ wt,
                                                 const float* __restrict__ dinv,
                                                 _Float16* __restrict__ out) {
    __shared__ h4 Wl[4096];  // 32 KB swizzled W^T
    {
        const float4* src = (const float4*)wt;
        float4* dst = (float4*)Wl;
        #pragma unroll
        for (int i = 0; i < 8; ++i) dst[threadIdx.x + i * 256] = src[threadIdx.x + i * 256];
    }
    __syncthreads();

    const int wave = threadIdx.x >> 6;
    const int lane = threadIdx.x & 63;
    const int m0 = blockIdx.x * 64 + wave * 16;
    if (m0 >= N_NODES) return;   // N_NODES % 16 == 0

    const int row = lane & 15;   // m-offset (B col) / n-offset (A row)
    const int g   = lane >> 4;   // k-group
    const int m   = m0 + row;
    const TIN* arow = in + (size_t)m * DIM;
    const float di = dinv[m];

    f32x4 acc[8] = {};  // 8 n-tiles of 16 cols

    #pragma unroll
    for (int kc = 0; kc < 8; ++kc) {
        const int k = kc * 16 + g * 4;
        const h4 bfrag = loadfrag(arow + k);        // B[k..k+3][m]
        const int u = kc * 4 + g;
        #pragma unroll
        for (int nb = 0; nb < 8; ++nb) {
            const int n = nb * 16 + row;
            const h4 afrag = Wl[n * 32 + (u ^ (n & 31))];  // A[n][k..k+3]
            acc[nb] = __builtin_amdgcn_mfma_f32_16x16x16f16(afrag, bfrag, acc[nb], 0, 0, 0);
        }
    }

    _Float16* orow = out + (size_t)m * DIM;
    #pragma unroll
    for (int nb = 0; nb < 8; ++nb) {
        h4 v;
        v.x = (_Float16)(acc[nb].x * di); v.y = (_Float16)(acc[nb].y * di);
        v.z = (_Float16)(acc[nb].z * di); v.w = (_Float16)(acc[nb].w * di);
        ((h4*)orow)[nb * 4 + g] = v;
    }
}

// ---------------- fused aggregate + scale + bias + relu ----------------
// hw holds dinv_s-prescaled rows; gather is pure packed-fp16 adds, final scale by dinv_d.
// 8 groups of 8 lanes: stream = grp&3, half = grp>>2; 128B half-row per group.

__global__ __launch_bounds__(256) void gather_agg(const _Float16* __restrict__ hw,
                                                  const float* __restrict__ dinv,
                                                  const int* __restrict__ off,
                                                  const int* __restrict__ csr_src,
                                                  const float* __restrict__ bias,
                                                  _Float16* __restrict__ hout) {
    const int i = (blockIdx.x * blockDim.x + threadIdx.x) >> 6;  // node = wave id
    if (i >= N_NODES) return;
    const int lane = threadIdx.x & 63;
    const int grp    = lane >> 3;   // 0..7
    const int stream = grp & 3;     // edge stream
    const int half   = grp >> 2;    // row half
    const int sub    = lane & 7;    // h8 unit within half
    const int idx8   = half * 8 + sub;   // h8 index in row (16 per row)
    const h8* hw8 = (const h8*)hw;

    const int beg = off[i], end = off[i + 1];
    h8 acc = {};

    if (stream == 3) acc = hw8[(size_t)i * 16 + idx8];  // self-loop: += hw'_i

    int j = beg + stream;
    for (; j + 4 < end; j += 8) {
        int s0 = csr_src[j];
        int s1 = csr_src[j + 4];
        h8 v0 = hw8[(size_t)s0 * 16 + idx8];
        h8 v1 = hw8[(size_t)s1 * 16 + idx8];
        #pragma unroll
        for (int p = 0; p < 4; ++p) {
            ((h2*)&acc)[p] += ((h2*)&v0)[p];
            ((h2*)&acc)[p] += ((h2*)&v1)[p];
        }
    }
    for (; j < end; j += 4) {
        int s0 = csr_src[j];
        h8 v0 = hw8[(size_t)s0 * 16 + idx8];
        #pragma unroll
        for (int p = 0; p < 4; ++p) ((h2*)&acc)[p] += ((h2*)&v0)[p];
    }

    // packed fp16 reduce across the 4 streams (lane bits 3,4)
    unsigned int* au = (unsigned int*)&acc;
    #pragma unroll
    for (int p = 0; p < 4; ++p) {
        unsigned int o = __shfl_xor(au[p], 8);
        h2 a = *(h2*)&au[p]; a += *(h2*)&o; au[p] = *(unsigned int*)&a;
        o = __shfl_xor(au[p], 16);
        h2 b = *(h2*)&au[p]; b += *(h2*)&o; au[p] = *(unsigned int*)&b;
    }

    if (stream == 0) {  // grp 0 (half 0) and grp 4 (half 1) write their half
        const float di = dinv[i];
        const float4 b0 = *(const float4*)&bias[half * 64 + sub * 8];
        const float4 b1 = *(const float4*)&bias[half * 64 + sub * 8 + 4];
        h8 v;
        v[0] = (_Float16)fmaxf((float)acc[0] * di + b0.x, 0.0f);
        v[1] = (_Float16)fmaxf((float)acc[1] * di + b0.y, 0.0f);
        v[2] = (_Float16)fmaxf((float)acc[2] * di + b0.z, 0.0f);
        v[3] = (_Float16)fmaxf((float)acc[3] * di + b0.w, 0.0f);
        v[4] = (_Float16)fmaxf((float)acc[4] * di + b1.x, 0.0f);
        v[5] = (_Float16)fmaxf((float)acc[5] * di + b1.y, 0.0f);
        v[6] = (_Float16)fmaxf((float)acc[6] * di + b1.z, 0.0f);
        v[7] = (_Float16)fmaxf((float)acc[7] * di + b1.w, 0.0f);
        ((h8*)hout)[(size_t)i * 16 + idx8] = v;
    }
}

// ---------------- chunked segmented pool (batch sorted) ----------------

__global__ __launch_bounds__(256) void pool_chunk(const _Float16* __restrict__ h,
                                                  const int* __restrict__ batch,
                                                  float* __restrict__ pooled) {
    const int base = blockIdx.x * PCHUNK;
    const int t = threadIdx.x;
    const int lane4 = t & 31;    // dims lane4*4 .. +3
    const int rgrp = t >> 5;     // 0..7
    const h4* hp = (const h4*)h; // row stride 32

    float a0 = 0.f, a1 = 0.f, a2 = 0.f, a3 = 0.f;
    int cur = -1;
    const int rend = (base + PCHUNK < N_NODES) ? base + PCHUNK : N_NODES;
    for (int r = base + rgrp; r < rend; r += 8) {
        int b = batch[r];
        if (b != cur) {
            if (cur >= 0) {
                float* pp = &pooled[cur * DIM + lane4 * 4];
                atomicAdd(pp + 0, a0); atomicAdd(pp + 1, a1);
                atomicAdd(pp + 2, a2); atomicAdd(pp + 3, a3);
            }
            cur = b; a0 = a1 = a2 = a3 = 0.f;
        }
        h4 v = hp[(size_t)r * 32 + lane4];
        a0 += (float)v.x; a1 += (float)v.y; a2 += (float)v.z; a3 += (float)v.w;
    }
    if (cur >= 0) {
        float* pp = &pooled[cur * DIM + lane4 * 4];
        atomicAdd(pp + 0, a0); atomicAdd(pp + 1, a1);
        atomicAdd(pp + 2, a2); atomicAdd(pp + 3, a3);
    }
}

// ---------------- head ----------------

__global__ void mlp_head(const float* __restrict__ pooled, const float* __restrict__ Wm,
                         const float* __restrict__ bm, float* __restrict__ out) {
    int t = blockIdx.x * blockDim.x + threadIdx.x;
    if (t >= N_GRAPHS * N_OUT) return;
    int b = t / N_OUT;
    int o = t % N_OUT;
    float acc = bm[o];
    #pragma unroll 8
    for (int k = 0; k < DIM; ++k) acc += pooled[b * DIM + k] * Wm[k * N_OUT + o];
    out[t] = acc;
}

// ---------------- launch ----------------

extern "C" void kernel_launch(void* const* d_in, const int* in_sizes, int n_in,
                              void* d_out, int out_size, void* d_ws, size_t ws_size,
                              hipStream_t stream) {
    const float* x     = (const float*)d_in[0];
    const int*   ei    = (const int*)d_in[1];
    const int*   batch = (const int*)d_in[2];
    const float* Ws    = (const float*)d_in[3];
    const float* bs    = (const float*)d_in[4];
    const float* Wm    = (const float*)d_in[5];
    const float* bm    = (const float*)d_in[6];
    float* out = (float*)d_out;

    // workspace carve-up (16B aligned regions; cnt+cursor adjacent for one memset)
    char* p = (char*)d_ws;
    int*      cnt     = (int*)p;        p += N_NODES * 4;
    int*      cursor  = (int*)p;        p += N_NODES * 4;
    float*    dinv    = (float*)p;      p += N_NODES * 4;
    int*      csr_off = (int*)p;        p += (N_NODES + 16) * 4;
    int*      bsum    = (int*)p;        p += 128 * 4;
    _Float16* wt      = (_Float16*)p;   p += (size_t)N_LAYERS * DIM * DIM * 2;  // swizzled W^T fp16
    int*      csr_src = (int*)p;        p += (size_t)N_EDGES * 4;
    _Float16* bufA    = (_Float16*)p;   p += (size_t)N_NODES * DIM * 2;  // hw' (dinv-prescaled)
    _Float16* bufB    = (_Float16*)p;   p += (size_t)N_NODES * DIM * 2;  // h
    float*    pooled  = (float*)p;      p += N_GRAPHS * DIM * 4;

    const int nnode_blk = (N_NODES + 255) / 256;
    const int nedge_blk = (N_EDGES + 255) / 256;

    hipMemsetAsync(cnt, 0, N_NODES * 8, stream);  // cnt + cursor
    hipMemsetAsync(pooled, 0, N_GRAPHS * DIM * 4, stream);

    hist_dst<<<nedge_blk, 256, 0, stream>>>(ei, cnt);
    wt_prep<<<(N_LAYERS * DIM * 32 + 255) / 256, 256, 0, stream>>>(Ws, wt);

    scan1<<<N_SCAN_BLKS, 256, 0, stream>>>(cnt, csr_off, bsum, dinv);
    scan2<<<1, 128, 0, stream>>>(bsum);
    scan3<<<nnode_blk, 256, 0, stream>>>(csr_off, bsum);

    fill_csr<<<nedge_blk, 256, 0, stream>>>(ei, csr_off, cursor, csr_src);

    const int gemm_grid = (N_NODES + 63) / 64;           // 1563
    const int gather_grid = (N_NODES * 64 + 255) / 256;  // one wave per node
    for (int l = 0; l < N_LAYERS; ++l) {
        if (l == 0) gemm_mfma<float><<<gemm_grid, 256, 0, stream>>>(x, wt, dinv, bufA);
        else        gemm_mfma<_Float16><<<gemm_grid, 256, 0, stream>>>(bufB, wt + (size_t)l * DIM * DIM, dinv, bufA);
        gather_agg<<<gather_grid, 256, 0, stream>>>(bufA, dinv, csr_off, csr_src, bs + l * DIM, bufB);
    }

    pool_chunk<<<(N_NODES + PCHUNK - 1) / PCHUNK, 256, 0, stream>>>(bufB, batch, pooled);
    mlp_head<<<(N_GRAPHS * N_OUT + 255) / 256, 256, 0, stream>>>(pooled, Wm, bm, out);
}